// Round 1
// baseline (936.342 us; speedup 1.0000x reference)
//
#include <hip/hip_runtime.h>
#include <cstdint>
#include <cstddef>

#define NUSER 100000
#define NITEM 50000
#define NEDGE 500000
#define NEG_SLOPE 0.01f

// ---------------- CSR build ----------------

__global__ void count_deg(const int* __restrict__ dst_rates, const int* __restrict__ dst_rev,
                          int* __restrict__ deg_item, int* __restrict__ deg_user) {
    int e = blockIdx.x * blockDim.x + threadIdx.x;
    if (e < NEDGE) {
        atomicAdd(&deg_item[dst_rates[e]], 1);
        atomicAdd(&deg_user[dst_rev[e]], 1);
    }
}

// block 0: item array (N=NITEM), block 1: user array (N=NUSER).
// In-place exclusive scan of deg -> row_ptr, also writes cursor copy, and row_ptr[N]=total.
__global__ void scan_two(int* __restrict__ rp_item, int* __restrict__ cur_item,
                         int* __restrict__ rp_user, int* __restrict__ cur_user) {
    int* d; int* cur; int N;
    if (blockIdx.x == 0) { d = rp_item; cur = cur_item; N = NITEM; }
    else                 { d = rp_user; cur = cur_user; N = NUSER; }
    const int T = 1024;
    int t = threadIdx.x;
    int C = (N + T - 1) / T;
    int beg = t * C;
    int end = beg + C; if (end > N) end = N;
    int mysum = 0;
    for (int j = beg; j < end; ++j) mysum += d[j];
    __shared__ int sm[1024];
    sm[t] = mysum;
    __syncthreads();
    for (int off = 1; off < T; off <<= 1) {
        int v = (t >= off) ? sm[t - off] : 0;
        __syncthreads();
        sm[t] += v;
        __syncthreads();
    }
    int run = sm[t] - mysum;   // exclusive prefix
    for (int j = beg; j < end; ++j) {
        int v = d[j];
        d[j] = run;
        cur[j] = run;
        run += v;
    }
    if (t == 0) d[N] = sm[T - 1];
}

__global__ void fill_csr(const int* __restrict__ src_rates, const int* __restrict__ dst_rates,
                         const int* __restrict__ src_rev,   const int* __restrict__ dst_rev,
                         int* __restrict__ cur_item, int* __restrict__ csr_item,
                         int* __restrict__ cur_user, int* __restrict__ csr_user) {
    int e = blockIdx.x * blockDim.x + threadIdx.x;
    if (e < NEDGE) {
        int di = dst_rates[e];
        int p = atomicAdd(&cur_item[di], 1);
        csr_item[p] = src_rates[e];
        int du = dst_rev[e];
        int q = atomicAdd(&cur_user[du], 1);
        csr_user[q] = src_rev[e];
    }
}

// ---------------- Aggregation: out[i] = (1/max(deg,1)) * sum_{j in row i} feat[csr[j]] ----------------
// one wave per dst row; lane holds features (2*lane, 2*lane+1)

__global__ void aggregate(const float* __restrict__ feat, const int* __restrict__ rp,
                          const int* __restrict__ csr, float* __restrict__ out, int N) {
    int row = blockIdx.x * 4 + (threadIdx.x >> 6);
    if (row >= N) return;
    int lane = threadIdx.x & 63;
    int b = rp[row], e = rp[row + 1];
    float accx = 0.f, accy = 0.f;
    for (int j = b; j < e; ++j) {
        int s = csr[j];
        const float2 v = *((const float2*)(feat + (size_t)s * 128) + lane);
        accx += v.x;
        accy += v.y;
    }
    int deg = e - b;
    float inv = 1.0f / (float)(deg > 0 ? deg : 1);
    float2 o; o.x = accx * inv; o.y = accy * inv;
    *((float2*)(out + (size_t)row * 128) + lane) = o;
}

// ---------------- GEMM: out[N x 128] = in[N x 128] @ W[128 x 128] + bias, optional leaky ----------------
// block = 256 threads, 32-row tile. W (64KB) + x-tile (16KB) in LDS -> 2 blocks/CU.
// In-place safe: tile staged to LDS before any global write of the same rows.

__global__ __launch_bounds__(256) void gemm128(const float* __restrict__ in, const float* __restrict__ W,
                                               const float* __restrict__ bias, float* __restrict__ out,
                                               int N, int leaky) {
    __shared__ float wl[128 * 128];
    __shared__ float xl[32 * 128];
    int t = threadIdx.x;

    // stage W: 4096 float4
    const float4* W4 = (const float4*)W;
    float4* wl4 = (float4*)wl;
    for (int i = t; i < 4096; i += 256) wl4[i] = W4[i];

    // stage x tile: 1024 float4 (32 float4 per row)
    int row0 = blockIdx.x * 32;
    const float4* in4 = (const float4*)(in + (size_t)row0 * 128);
    float4* xl4 = (float4*)xl;
    for (int i = t; i < 1024; i += 256) {
        int r = i >> 5;
        float4 v;
        if (row0 + r < N) v = in4[i];
        else { v.x = v.y = v.z = v.w = 0.f; }
        xl4[i] = v;
    }
    __syncthreads();

    int c0 = (t & 31) * 4;   // 4 output cols
    int r0 = (t >> 5) * 4;   // 4 rows
    float4 acc[4];
    for (int r = 0; r < 4; ++r) { acc[r].x = acc[r].y = acc[r].z = acc[r].w = 0.f; }

    #pragma unroll 8
    for (int k4 = 0; k4 < 32; ++k4) {
        float4 xf[4];
        #pragma unroll
        for (int r = 0; r < 4; ++r) xf[r] = *(const float4*)&xl[(r0 + r) * 128 + k4 * 4];
        #pragma unroll
        for (int kk = 0; kk < 4; ++kk) {
            float4 wv = *(const float4*)&wl[(k4 * 4 + kk) * 128 + c0];
            #pragma unroll
            for (int r = 0; r < 4; ++r) {
                float a = ((const float*)&xf[r])[kk];
                acc[r].x += a * wv.x;
                acc[r].y += a * wv.y;
                acc[r].z += a * wv.z;
                acc[r].w += a * wv.w;
            }
        }
    }

    float4 bv = *(const float4*)&bias[c0];
    #pragma unroll
    for (int r = 0; r < 4; ++r) {
        int row = row0 + r0 + r;
        if (row < N) {
            float4 o;
            o.x = acc[r].x + bv.x;
            o.y = acc[r].y + bv.y;
            o.z = acc[r].z + bv.z;
            o.w = acc[r].w + bv.w;
            if (leaky) {
                o.x = o.x > 0.f ? o.x : NEG_SLOPE * o.x;
                o.y = o.y > 0.f ? o.y : NEG_SLOPE * o.y;
                o.z = o.z > 0.f ? o.z : NEG_SLOPE * o.z;
                o.w = o.w > 0.f ? o.w : NEG_SLOPE * o.w;
            }
            *(float4*)(out + (size_t)row * 128 + c0) = o;
        }
    }
}

// ---------------- launch ----------------

extern "C" void kernel_launch(void* const* d_in, const int* in_sizes, int n_in,
                              void* d_out, int out_size, void* d_ws, size_t ws_size,
                              hipStream_t stream) {
    const float* x_user   = (const float*)d_in[0];
    const float* x_item   = (const float*)d_in[1];
    const int*   src_rates = (const int*)d_in[2];
    const int*   dst_rates = (const int*)d_in[3];
    const int*   src_rev   = (const int*)d_in[4];
    const int*   dst_rev   = (const int*)d_in[5];
    const float* W1_rates = (const float*)d_in[6];
    const float* b1_rates = (const float*)d_in[7];
    const float* W1_rev   = (const float*)d_in[8];
    const float* b1_rev   = (const float*)d_in[9];
    const float* W2_rates = (const float*)d_in[10];
    const float* b2_rates = (const float*)d_in[11];
    const float* W2_rev   = (const float*)d_in[12];
    const float* b2_rev   = (const float*)d_in[13];

    float* out    = (float*)d_out;
    float* o_user = out;                          // [NUSER,128]
    float* o_item = out + (size_t)NUSER * 128;    // [NITEM,128]

    // workspace carve-up
    char* ws = (char*)d_ws;
    size_t off = 0;
    auto carve = [&](size_t bytes) -> void* {
        void* p = ws + off;
        off = (off + bytes + 255) & ~(size_t)255;
        return p;
    };
    float* agg_item = (float*)carve((size_t)NITEM * 128 * 4);  // aggx_item, then h_item (in-place)
    float* agg_user = (float*)carve((size_t)NUSER * 128 * 4);  // aggx_user, then h_user (in-place)
    int* rp_item  = (int*)carve((size_t)(NITEM + 1) * 4);
    int* rp_user  = (int*)carve((size_t)(NUSER + 1) * 4);
    int* cur_item = (int*)carve((size_t)NITEM * 4);
    int* cur_user = (int*)carve((size_t)NUSER * 4);
    int* csr_item = (int*)carve((size_t)NEDGE * 4);
    int* csr_user = (int*)carve((size_t)NEDGE * 4);

    // --- CSR build (shared by both layers) ---
    hipMemsetAsync(rp_item, 0, (size_t)(NITEM + 1) * 4, stream);
    hipMemsetAsync(rp_user, 0, (size_t)(NUSER + 1) * 4, stream);
    int eb = (NEDGE + 255) / 256;
    count_deg<<<eb, 256, 0, stream>>>(dst_rates, dst_rev, rp_item, rp_user);
    scan_two<<<2, 1024, 0, stream>>>(rp_item, cur_item, rp_user, cur_user);
    fill_csr<<<eb, 256, 0, stream>>>(src_rates, dst_rates, src_rev, dst_rev,
                                     cur_item, csr_item, cur_user, csr_user);

    // --- layer 1: aggregate raw features, then (agg @ W)/deg + b with leaky ---
    aggregate<<<(NITEM + 3) / 4, 256, 0, stream>>>(x_user, rp_item, csr_item, agg_item, NITEM);
    aggregate<<<(NUSER + 3) / 4, 256, 0, stream>>>(x_item, rp_user, csr_user, agg_user, NUSER);
    gemm128<<<(NITEM + 31) / 32, 256, 0, stream>>>(agg_item, W1_rates, b1_rates, agg_item, NITEM, 1);
    gemm128<<<(NUSER + 31) / 32, 256, 0, stream>>>(agg_user, W1_rev, b1_rev, agg_user, NUSER, 1);

    // --- layer 2: aggregate h into d_out, GEMM in-place on d_out ---
    aggregate<<<(NITEM + 3) / 4, 256, 0, stream>>>(agg_user /*h_user*/, rp_item, csr_item, o_item, NITEM);
    aggregate<<<(NUSER + 3) / 4, 256, 0, stream>>>(agg_item /*h_item*/, rp_user, csr_user, o_user, NUSER);
    gemm128<<<(NITEM + 31) / 32, 256, 0, stream>>>(o_item, W2_rates, b2_rates, o_item, NITEM, 0);
    gemm128<<<(NUSER + 31) / 32, 256, 0, stream>>>(o_user, W2_rev, b2_rev, o_user, NUSER, 0);
}

// Round 2
// 645.770 us; speedup vs baseline: 1.4500x; 1.4500x over previous
//
#include <hip/hip_runtime.h>
#include <cstdint>
#include <cstddef>

#define NUSER 100000
#define NITEM 50000
#define NTOT  150000          // NITEM + NUSER (item rows first, then user rows)
#define NEDGE 500000
#define NEG_SLOPE 0.01f
#define SCAN_CHUNK 2048       // elements per scan block (256 thr * 8)
#define SCAN_NBLK ((NTOT + SCAN_CHUNK - 1) / SCAN_CHUNK)   // 74

// ---------------- CSR build (combined: rows 0..NITEM) = item, rows NITEM..NTOT) = user) ----------------

__global__ void count_deg(const int* __restrict__ dst_rates, const int* __restrict__ dst_rev,
                          int* __restrict__ deg) {
    int e = blockIdx.x * blockDim.x + threadIdx.x;
    if (e < NEDGE) {
        atomicAdd(&deg[dst_rates[e]], 1);
        atomicAdd(&deg[NITEM + dst_rev[e]], 1);
    }
}

// per-block exclusive scan of 2048-element chunk, in place; block total -> bsums
__global__ __launch_bounds__(256) void scan_blocks(int* __restrict__ d, int* __restrict__ bsums) {
    __shared__ int sm[256];
    int t = threadIdx.x;
    int base = blockIdx.x * SCAN_CHUNK + t * 8;
    int v[8]; int s = 0;
    #pragma unroll
    for (int k = 0; k < 8; ++k) {
        int idx = base + k;
        v[k] = (idx < NTOT) ? d[idx] : 0;
        s += v[k];
    }
    sm[t] = s;
    __syncthreads();
    for (int off = 1; off < 256; off <<= 1) {
        int x = (t >= off) ? sm[t - off] : 0;
        __syncthreads();
        sm[t] += x;
        __syncthreads();
    }
    int run = sm[t] - s;           // exclusive prefix of this thread's 8
    if (t == 255) bsums[blockIdx.x] = sm[255];
    #pragma unroll
    for (int k = 0; k < 8; ++k) {
        int idx = base + k;
        if (idx < NTOT) d[idx] = run;
        run += v[k];
    }
}

// single block: exclusive scan of the block sums (SCAN_NBLK <= 256)
__global__ __launch_bounds__(256) void scan_tops(int* __restrict__ bsums) {
    __shared__ int sm[256];
    int t = threadIdx.x;
    int s = (t < SCAN_NBLK) ? bsums[t] : 0;
    sm[t] = s;
    __syncthreads();
    for (int off = 1; off < 256; off <<= 1) {
        int x = (t >= off) ? sm[t - off] : 0;
        __syncthreads();
        sm[t] += x;
        __syncthreads();
    }
    if (t < SCAN_NBLK) bsums[t] = sm[t] - s;
}

// add block offsets; produce final row_ptr (rp) and cursor copy; terminal entry
__global__ void add_off(int* __restrict__ rp, const int* __restrict__ bsums, int* __restrict__ cur) {
    int i = blockIdx.x * blockDim.x + threadIdx.x;
    if (i < NTOT) {
        int v = rp[i] + bsums[i / SCAN_CHUNK];
        rp[i] = v;
        cur[i] = v;
    }
    if (i == 0) rp[NTOT] = 2 * NEDGE;
}

__global__ void fill_csr(const int* __restrict__ src_rates, const int* __restrict__ dst_rates,
                         const int* __restrict__ src_rev,   const int* __restrict__ dst_rev,
                         int* __restrict__ cur, int* __restrict__ csr) {
    int e = blockIdx.x * blockDim.x + threadIdx.x;
    if (e < NEDGE) {
        int p = atomicAdd(&cur[dst_rates[e]], 1);
        csr[p] = src_rates[e];
        int q = atomicAdd(&cur[NITEM + dst_rev[e]], 1);
        csr[q] = src_rev[e];
    }
}

// ---------------- Aggregation ----------------
// one wave per dst row; half-wave h processes edges j = b+h, b+h+2, ...; lane&31 holds float4 col block.
// cross-half __shfl_xor(32) reduce, deg-normalize fused.

__global__ __launch_bounds__(256) void aggregate(const float* __restrict__ feat, const int* __restrict__ rp,
                                                 const int* __restrict__ csr, float* __restrict__ out, int N) {
    int row = blockIdx.x * 4 + (threadIdx.x >> 6);
    if (row >= N) return;
    int lane = threadIdx.x & 63;
    int half = lane >> 5;
    int l32 = lane & 31;
    int b = rp[row], e = rp[row + 1];
    float ax = 0.f, ay = 0.f, az = 0.f, aw = 0.f;
    for (int j = b + half; j < e; j += 2) {
        int s = csr[j];
        const float4 v = *((const float4*)(feat + (size_t)s * 128) + l32);
        ax += v.x; ay += v.y; az += v.z; aw += v.w;
    }
    // reduce across the two halves
    ax += __shfl_xor(ax, 32);
    ay += __shfl_xor(ay, 32);
    az += __shfl_xor(az, 32);
    aw += __shfl_xor(aw, 32);
    if (half == 0) {
        int deg = e - b;
        float inv = 1.0f / (float)(deg > 0 ? deg : 1);
        float4 o; o.x = ax * inv; o.y = ay * inv; o.z = az * inv; o.w = aw * inv;
        *((float4*)(out + (size_t)row * 128) + l32) = o;
    }
}

// ---------------- GEMM: out[N x 128] = in[N x 128] @ W[128 x 128] + bias, optional leaky ----------------

__global__ __launch_bounds__(256) void gemm128(const float* __restrict__ in, const float* __restrict__ W,
                                               const float* __restrict__ bias, float* __restrict__ out,
                                               int N, int leaky) {
    __shared__ float wl[128 * 128];
    __shared__ float xl[32 * 128];
    int t = threadIdx.x;

    const float4* W4 = (const float4*)W;
    float4* wl4 = (float4*)wl;
    for (int i = t; i < 4096; i += 256) wl4[i] = W4[i];

    int row0 = blockIdx.x * 32;
    const float4* in4 = (const float4*)(in + (size_t)row0 * 128);
    float4* xl4 = (float4*)xl;
    for (int i = t; i < 1024; i += 256) {
        int r = i >> 5;
        float4 v;
        if (row0 + r < N) v = in4[i];
        else { v.x = v.y = v.z = v.w = 0.f; }
        xl4[i] = v;
    }
    __syncthreads();

    int c0 = (t & 31) * 4;
    int r0 = (t >> 5) * 4;
    float4 acc[4];
    for (int r = 0; r < 4; ++r) { acc[r].x = acc[r].y = acc[r].z = acc[r].w = 0.f; }

    #pragma unroll 8
    for (int k4 = 0; k4 < 32; ++k4) {
        float4 xf[4];
        #pragma unroll
        for (int r = 0; r < 4; ++r) xf[r] = *(const float4*)&xl[(r0 + r) * 128 + k4 * 4];
        #pragma unroll
        for (int kk = 0; kk < 4; ++kk) {
            float4 wv = *(const float4*)&wl[(k4 * 4 + kk) * 128 + c0];
            #pragma unroll
            for (int r = 0; r < 4; ++r) {
                float a = ((const float*)&xf[r])[kk];
                acc[r].x += a * wv.x;
                acc[r].y += a * wv.y;
                acc[r].z += a * wv.z;
                acc[r].w += a * wv.w;
            }
        }
    }

    float4 bv = *(const float4*)&bias[c0];
    #pragma unroll
    for (int r = 0; r < 4; ++r) {
        int row = row0 + r0 + r;
        if (row < N) {
            float4 o;
            o.x = acc[r].x + bv.x;
            o.y = acc[r].y + bv.y;
            o.z = acc[r].z + bv.z;
            o.w = acc[r].w + bv.w;
            if (leaky) {
                o.x = o.x > 0.f ? o.x : NEG_SLOPE * o.x;
                o.y = o.y > 0.f ? o.y : NEG_SLOPE * o.y;
                o.z = o.z > 0.f ? o.z : NEG_SLOPE * o.z;
                o.w = o.w > 0.f ? o.w : NEG_SLOPE * o.w;
            }
            *(float4*)(out + (size_t)row * 128 + c0) = o;
        }
    }
}

// ---------------- launch ----------------

extern "C" void kernel_launch(void* const* d_in, const int* in_sizes, int n_in,
                              void* d_out, int out_size, void* d_ws, size_t ws_size,
                              hipStream_t stream) {
    const float* x_user   = (const float*)d_in[0];
    const float* x_item   = (const float*)d_in[1];
    const int*   src_rates = (const int*)d_in[2];
    const int*   dst_rates = (const int*)d_in[3];
    const int*   src_rev   = (const int*)d_in[4];
    const int*   dst_rev   = (const int*)d_in[5];
    const float* W1_rates = (const float*)d_in[6];
    const float* b1_rates = (const float*)d_in[7];
    const float* W1_rev   = (const float*)d_in[8];
    const float* b1_rev   = (const float*)d_in[9];
    const float* W2_rates = (const float*)d_in[10];
    const float* b2_rates = (const float*)d_in[11];
    const float* W2_rev   = (const float*)d_in[12];
    const float* b2_rev   = (const float*)d_in[13];

    float* out    = (float*)d_out;
    float* o_user = out;                          // [NUSER,128]
    float* o_item = out + (size_t)NUSER * 128;    // [NITEM,128]

    char* ws = (char*)d_ws;
    size_t off = 0;
    auto carve = [&](size_t bytes) -> void* {
        void* p = ws + off;
        off = (off + bytes + 255) & ~(size_t)255;
        return p;
    };
    float* agg_item = (float*)carve((size_t)NITEM * 128 * 4);   // then h_item (in-place)
    float* agg_user = (float*)carve((size_t)NUSER * 128 * 4);   // then h_user (in-place)
    int* rp    = (int*)carve((size_t)(NTOT + 1) * 4);           // combined row_ptr
    int* cur   = (int*)carve((size_t)NTOT * 4);
    int* bsums = (int*)carve((size_t)SCAN_NBLK * 4);
    int* csr   = (int*)carve((size_t)(2 * NEDGE) * 4);          // combined adjacency

    // --- CSR build (shared by both layers) ---
    hipMemsetAsync(rp, 0, (size_t)(NTOT + 1) * 4, stream);
    int eb = (NEDGE + 255) / 256;
    count_deg<<<eb, 256, 0, stream>>>(dst_rates, dst_rev, rp);
    scan_blocks<<<SCAN_NBLK, 256, 0, stream>>>(rp, bsums);
    scan_tops<<<1, 256, 0, stream>>>(bsums);
    add_off<<<(NTOT + 255) / 256, 256, 0, stream>>>(rp, bsums, cur);
    fill_csr<<<eb, 256, 0, stream>>>(src_rates, dst_rates, src_rev, dst_rev, cur, csr);

    const int* rp_item = rp;           // rows [0, NITEM)
    const int* rp_user = rp + NITEM;   // rows [0, NUSER)

    // --- layer 1: aggregate raw features, then (agg @ W)/deg + b with leaky ---
    aggregate<<<(NITEM + 3) / 4, 256, 0, stream>>>(x_user, rp_item, csr, agg_item, NITEM);
    aggregate<<<(NUSER + 3) / 4, 256, 0, stream>>>(x_item, rp_user, csr, agg_user, NUSER);
    gemm128<<<(NITEM + 31) / 32, 256, 0, stream>>>(agg_item, W1_rates, b1_rates, agg_item, NITEM, 1);
    gemm128<<<(NUSER + 31) / 32, 256, 0, stream>>>(agg_user, W1_rev, b1_rev, agg_user, NUSER, 1);

    // --- layer 2: aggregate h into d_out, GEMM in-place on d_out ---
    aggregate<<<(NITEM + 3) / 4, 256, 0, stream>>>(agg_user /*h_user*/, rp_item, csr, o_item, NITEM);
    aggregate<<<(NUSER + 3) / 4, 256, 0, stream>>>(agg_item /*h_item*/, rp_user, csr, o_user, NUSER);
    gemm128<<<(NITEM + 31) / 32, 256, 0, stream>>>(o_item, W2_rates, b2_rates, o_item, NITEM, 0);
    gemm128<<<(NUSER + 31) / 32, 256, 0, stream>>>(o_user, W2_rev, b2_rev, o_user, NUSER, 0);
}

// Round 3
// 340.038 us; speedup vs baseline: 2.7536x; 1.8991x over previous
//
#include <hip/hip_runtime.h>
#include <cstdint>
#include <cstddef>

#define NUSER 100000
#define NITEM 50000
#define NTOT  150000          // NITEM + NUSER (item rows first, then user rows)
#define NEDGE 500000
#define NEG_SLOPE 0.01f
#define SCAN_CHUNK 2048
#define SCAN_NBLK ((NTOT + SCAN_CHUNK - 1) / SCAN_CHUNK)   // 74
#define PADW 136              // 128 + 8 bf16 pad (16B) -> conflict-free ds_read_b128

typedef __attribute__((ext_vector_type(8))) short bf16x8;
typedef __attribute__((ext_vector_type(4))) float f32x4;

__device__ __forceinline__ unsigned short f2bf(float f) {
    unsigned int u = __builtin_bit_cast(unsigned int, f);
    unsigned int r = u + 0x7fffu + ((u >> 16) & 1u);   // RNE
    return (unsigned short)(r >> 16);
}
__device__ __forceinline__ float bf2f(unsigned int b) {
    unsigned int u = (b & 0xffffu) << 16;
    return __builtin_bit_cast(float, u);
}
__device__ __forceinline__ unsigned int pack2(float lo, float hi) {
    return (unsigned int)f2bf(lo) | ((unsigned int)f2bf(hi) << 16);
}

// ---------------- CSR build (combined rows: [0,NITEM)=item, [NITEM,NTOT)=user) ----------------

__global__ void count_deg(const int* __restrict__ dst_rates, const int* __restrict__ dst_rev,
                          int* __restrict__ deg) {
    int e = blockIdx.x * blockDim.x + threadIdx.x;
    if (e < NEDGE) {
        atomicAdd(&deg[dst_rates[e]], 1);
        atomicAdd(&deg[NITEM + dst_rev[e]], 1);
    }
}

__global__ __launch_bounds__(256) void scan_blocks(int* __restrict__ d, int* __restrict__ bsums) {
    __shared__ int sm[256];
    int t = threadIdx.x;
    int base = blockIdx.x * SCAN_CHUNK + t * 8;
    int v[8]; int s = 0;
    #pragma unroll
    for (int k = 0; k < 8; ++k) {
        int idx = base + k;
        v[k] = (idx < NTOT) ? d[idx] : 0;
        s += v[k];
    }
    sm[t] = s;
    __syncthreads();
    for (int off = 1; off < 256; off <<= 1) {
        int x = (t >= off) ? sm[t - off] : 0;
        __syncthreads();
        sm[t] += x;
        __syncthreads();
    }
    int run = sm[t] - s;
    if (t == 255) bsums[blockIdx.x] = sm[255];
    #pragma unroll
    for (int k = 0; k < 8; ++k) {
        int idx = base + k;
        if (idx < NTOT) d[idx] = run;
        run += v[k];
    }
}

__global__ __launch_bounds__(256) void scan_tops(int* __restrict__ bsums) {
    __shared__ int sm[256];
    int t = threadIdx.x;
    int s = (t < SCAN_NBLK) ? bsums[t] : 0;
    sm[t] = s;
    __syncthreads();
    for (int off = 1; off < 256; off <<= 1) {
        int x = (t >= off) ? sm[t - off] : 0;
        __syncthreads();
        sm[t] += x;
        __syncthreads();
    }
    if (t < SCAN_NBLK) bsums[t] = sm[t] - s;
}

__global__ void add_off(int* __restrict__ rp, const int* __restrict__ bsums, int* __restrict__ cur) {
    int i = blockIdx.x * blockDim.x + threadIdx.x;
    if (i < NTOT) {
        int v = rp[i] + bsums[i / SCAN_CHUNK];
        rp[i] = v;
        cur[i] = v;
    }
    if (i == 0) rp[NTOT] = 2 * NEDGE;
}

__global__ void fill_csr(const int* __restrict__ src_rates, const int* __restrict__ dst_rates,
                         const int* __restrict__ src_rev,   const int* __restrict__ dst_rev,
                         int* __restrict__ cur, int* __restrict__ csr) {
    int e = blockIdx.x * blockDim.x + threadIdx.x;
    if (e < NEDGE) {
        int p = atomicAdd(&cur[dst_rates[e]], 1);
        csr[p] = src_rates[e];
        int q = atomicAdd(&cur[NITEM + dst_rev[e]], 1);
        csr[q] = src_rev[e];
    }
}

// ---------------- weight prep: W[128][128] fp32 -> Wt bf16 [col][k] padded PADW ----------------

__global__ void wprep(const float* __restrict__ w0, const float* __restrict__ w1,
                      const float* __restrict__ w2, const float* __restrict__ w3,
                      unsigned short* __restrict__ wt) {
    const float* src = (blockIdx.x == 0) ? w0 : (blockIdx.x == 1) ? w1 : (blockIdx.x == 2) ? w2 : w3;
    unsigned short* dst = wt + (size_t)blockIdx.x * 128 * PADW;
    for (int i = threadIdx.x; i < 16384; i += 256) {
        int k = i >> 7, c = i & 127;
        dst[c * PADW + k] = f2bf(src[i]);
    }
}

// ---------------- x -> bf16 convert (both feature tables, one launch) ----------------

__global__ void cvt_bf(const float* __restrict__ xu, const float* __restrict__ xi,
                       unsigned short* __restrict__ dst) {
    const int n8u = NUSER * 128 / 8;
    const int n8  = (NUSER + NITEM) * 128 / 8;
    for (int i = blockIdx.x * blockDim.x + threadIdx.x; i < n8; i += gridDim.x * blockDim.x) {
        const float* s = (i < n8u) ? (xu + (size_t)i * 8) : (xi + (size_t)(i - n8u) * 8);
        float4 a = ((const float4*)s)[0];
        float4 b = ((const float4*)s)[1];
        uint4 o;
        o.x = pack2(a.x, a.y);
        o.y = pack2(a.z, a.w);
        o.z = pack2(b.x, b.y);
        o.w = pack2(b.z, b.w);
        ((uint4*)dst)[i] = o;
    }
}

// ---------------- aggregation (bf16 in -> bf16 out), both relations in one grid ----------------
// half-wave (32 lanes) per row: 2 edges in flight (sub=0/1), 16 lanes x 16B (8 bf16) per edge row.

__global__ __launch_bounds__(256) void aggregate_bf(const unsigned short* __restrict__ featA,  // for item rows
                                                    const unsigned short* __restrict__ featB,  // for user rows
                                                    const int* __restrict__ rp, const int* __restrict__ csr,
                                                    unsigned short* __restrict__ outb) {
    int row = blockIdx.x * 8 + (threadIdx.x >> 5);
    if (row >= NTOT) return;
    const unsigned short* feat = (row < NITEM) ? featA : featB;
    int l = threadIdx.x & 31;
    int sub = l >> 4, l16 = l & 15;
    int b = rp[row], e = rp[row + 1];
    float a0 = 0.f, a1 = 0.f, a2 = 0.f, a3 = 0.f, a4 = 0.f, a5 = 0.f, a6 = 0.f, a7 = 0.f;
    for (int j = b + sub; j < e; j += 2) {
        int s = csr[j];
        uint4 v = *((const uint4*)(feat + (size_t)s * 128) + l16);
        a0 += bf2f(v.x); a1 += bf2f(v.x >> 16);
        a2 += bf2f(v.y); a3 += bf2f(v.y >> 16);
        a4 += bf2f(v.z); a5 += bf2f(v.z >> 16);
        a6 += bf2f(v.w); a7 += bf2f(v.w >> 16);
    }
    a0 += __shfl_xor(a0, 16); a1 += __shfl_xor(a1, 16);
    a2 += __shfl_xor(a2, 16); a3 += __shfl_xor(a3, 16);
    a4 += __shfl_xor(a4, 16); a5 += __shfl_xor(a5, 16);
    a6 += __shfl_xor(a6, 16); a7 += __shfl_xor(a7, 16);
    if (sub == 0) {
        int deg = e - b;
        float inv = 1.0f / (float)(deg > 0 ? deg : 1);
        uint4 o;
        o.x = pack2(a0 * inv, a1 * inv);
        o.y = pack2(a2 * inv, a3 * inv);
        o.z = pack2(a4 * inv, a5 * inv);
        o.w = pack2(a6 * inv, a7 * inv);
        *((uint4*)(outb + (size_t)row * 128) + l16) = o;
    }
}

// ---------------- MFMA GEMM: out[N][128] = bf16 in[N][128] @ W + bias (+leaky) ----------------
// 64 rows/block, 4 waves (16 rows each). Wt prepacked [col][k] bf16 padded PADW.

__global__ __launch_bounds__(256) void gemm_mfma(const unsigned short* __restrict__ in,
                                                 const unsigned short* __restrict__ wt,
                                                 const float* __restrict__ bias,
                                                 float* __restrict__ outF,             // fp32 path if non-null
                                                 unsigned short* __restrict__ outB,    // bf16 path otherwise
                                                 int N, int leaky) {
    __shared__ __attribute__((aligned(16))) unsigned short wl[128 * PADW];  // 34816 B
    __shared__ __attribute__((aligned(16))) unsigned short xl[64 * PADW];   // 17408 B
    int t = threadIdx.x;
    int row0 = blockIdx.x * 64;

    // stage Wt (straight copy, prepacked with pad)
    for (int i = t; i < 128 * PADW / 8; i += 256)            // 2176 uint4
        ((uint4*)wl)[i] = ((const uint4*)wt)[i];

    // stage x tile as bf16 (16 B units: 64 rows x 16)
    for (int i = t; i < 1024; i += 256) {
        int r = i >> 4, c = i & 15;
        int row = row0 + r;
        uint4 v = make_uint4(0u, 0u, 0u, 0u);
        if (row < N) v = ((const uint4*)(in + (size_t)row * 128))[c];
        ((uint4*)xl)[r * (PADW / 8) + c] = v;                // PADW/8 = 17 uint4 per row
    }
    __syncthreads();

    int lane = t & 63, w = t >> 6;
    int l16 = lane & 15, kq = lane >> 4;
    int rowb = w * 16;

    f32x4 acc[8];
    #pragma unroll
    for (int i = 0; i < 8; ++i) acc[i] = (f32x4){0.f, 0.f, 0.f, 0.f};

    #pragma unroll
    for (int ks = 0; ks < 4; ++ks) {
        int ko = ks * 32 + kq * 8;
        bf16x8 af = *(const bf16x8*)&xl[(rowb + l16) * PADW + ko];
        #pragma unroll
        for (int t8 = 0; t8 < 8; ++t8) {
            bf16x8 bf = *(const bf16x8*)&wl[(t8 * 16 + l16) * PADW + ko];
            acc[t8] = __builtin_amdgcn_mfma_f32_16x16x32_bf16(af, bf, acc[t8], 0, 0, 0);
        }
    }

    float bv[8];
    #pragma unroll
    for (int t8 = 0; t8 < 8; ++t8) bv[t8] = bias[t8 * 16 + l16];

    if (outF) {
        #pragma unroll
        for (int t8 = 0; t8 < 8; ++t8) {
            #pragma unroll
            for (int j = 0; j < 4; ++j) {
                int row = row0 + rowb + kq * 4 + j;
                if (row < N) {
                    float v = acc[t8][j] + bv[t8];
                    if (leaky) v = v > 0.f ? v : NEG_SLOPE * v;
                    outF[(size_t)row * 128 + t8 * 16 + l16] = v;
                }
            }
        }
    } else {
        // bounce through xl (each wave writes only its own 16-row strip) for coalesced bf16 stores
        #pragma unroll
        for (int t8 = 0; t8 < 8; ++t8) {
            #pragma unroll
            for (int j = 0; j < 4; ++j) {
                float v = acc[t8][j] + bv[t8];
                if (leaky) v = v > 0.f ? v : NEG_SLOPE * v;
                xl[(rowb + kq * 4 + j) * PADW + t8 * 16 + l16] = f2bf(v);
            }
        }
        __syncthreads();
        for (int i = t; i < 1024; i += 256) {
            int r = i >> 4, c = i & 15;
            int row = row0 + r;
            if (row < N)
                ((uint4*)(outB + (size_t)row * 128))[c] = ((uint4*)xl)[r * (PADW / 8) + c];
        }
    }
}

// ---------------- launch ----------------

extern "C" void kernel_launch(void* const* d_in, const int* in_sizes, int n_in,
                              void* d_out, int out_size, void* d_ws, size_t ws_size,
                              hipStream_t stream) {
    const float* x_user    = (const float*)d_in[0];
    const float* x_item    = (const float*)d_in[1];
    const int*   src_rates = (const int*)d_in[2];
    const int*   dst_rates = (const int*)d_in[3];
    const int*   src_rev   = (const int*)d_in[4];
    const int*   dst_rev   = (const int*)d_in[5];
    const float* W1_rates  = (const float*)d_in[6];
    const float* b1_rates  = (const float*)d_in[7];
    const float* W1_rev    = (const float*)d_in[8];
    const float* b1_rev    = (const float*)d_in[9];
    const float* W2_rates  = (const float*)d_in[10];
    const float* b2_rates  = (const float*)d_in[11];
    const float* W2_rev    = (const float*)d_in[12];
    const float* b2_rev    = (const float*)d_in[13];

    float* out    = (float*)d_out;
    float* o_user = out;                          // [NUSER,128] fp32
    float* o_item = out + (size_t)NUSER * 128;    // [NITEM,128] fp32

    char* ws = (char*)d_ws;
    size_t off = 0;
    auto carve = [&](size_t bytes) -> void* {
        void* p = ws + off;
        off = (off + bytes + 255) & ~(size_t)255;
        return p;
    };
    // A: first x_bf {xu[NU],xi[NI]}, later h {h_item[NI], h_user[NU]}  (19.2M ushorts)
    unsigned short* A = (unsigned short*)carve((size_t)NTOT * 128 * 2);
    // B: aggregate output {item rows, user rows}, reused for both layers
    unsigned short* B = (unsigned short*)carve((size_t)NTOT * 128 * 2);
    int* rp    = (int*)carve((size_t)(NTOT + 1) * 4);
    int* cur   = (int*)carve((size_t)NTOT * 4);
    int* bsums = (int*)carve((size_t)SCAN_NBLK * 4);
    int* csr   = (int*)carve((size_t)(2 * NEDGE) * 4);
    unsigned short* wtAll = (unsigned short*)carve((size_t)4 * 128 * PADW * 2);
    unsigned short* Wt1_rates = wtAll;
    unsigned short* Wt1_rev   = wtAll + 1 * 128 * PADW;
    unsigned short* Wt2_rates = wtAll + 2 * (size_t)128 * PADW;
    unsigned short* Wt2_rev   = wtAll + 3 * (size_t)128 * PADW;

    unsigned short* xu_bf = A;
    unsigned short* xi_bf = A + (size_t)NUSER * 128;
    unsigned short* h_item = A;
    unsigned short* h_user = A + (size_t)NITEM * 128;
    unsigned short* agg_item = B;
    unsigned short* agg_user = B + (size_t)NITEM * 128;

    // --- CSR build ---
    hipMemsetAsync(rp, 0, (size_t)(NTOT + 1) * 4, stream);
    int eb = (NEDGE + 255) / 256;
    count_deg<<<eb, 256, 0, stream>>>(dst_rates, dst_rev, rp);
    scan_blocks<<<SCAN_NBLK, 256, 0, stream>>>(rp, bsums);
    scan_tops<<<1, 256, 0, stream>>>(bsums);
    add_off<<<(NTOT + 255) / 256, 256, 0, stream>>>(rp, bsums, cur);
    fill_csr<<<eb, 256, 0, stream>>>(src_rates, dst_rates, src_rev, dst_rev, cur, csr);

    // --- prep: weights + feature bf16 ---
    wprep<<<4, 256, 0, stream>>>(W1_rates, W1_rev, W2_rates, W2_rev, wtAll);
    cvt_bf<<<2048, 256, 0, stream>>>(x_user, x_item, A);

    int nbI = (NITEM + 63) / 64, nbU = (NUSER + 63) / 64;
    int nbAgg = (NTOT + 7) / 8;

    // --- layer 1 ---
    aggregate_bf<<<nbAgg, 256, 0, stream>>>(xu_bf, xi_bf, rp, csr, B);
    gemm_mfma<<<nbI, 256, 0, stream>>>(agg_item, Wt1_rates, b1_rates, nullptr, h_item, NITEM, 1);
    gemm_mfma<<<nbU, 256, 0, stream>>>(agg_user, Wt1_rev,   b1_rev,   nullptr, h_user, NUSER, 1);

    // --- layer 2 ---
    aggregate_bf<<<nbAgg, 256, 0, stream>>>(h_user, h_item, rp, csr, B);
    gemm_mfma<<<nbI, 256, 0, stream>>>(agg_item, Wt2_rates, b2_rates, o_item, nullptr, NITEM, 0);
    gemm_mfma<<<nbU, 256, 0, stream>>>(agg_user, Wt2_rev,   b2_rev,   o_user, nullptr, NUSER, 0);
}